// Round 1
// 299.551 us; speedup vs baseline: 1.1571x; 1.1571x over previous
//
#include <hip/hip_runtime.h>

// ---------------------------------------------------------------------------
// SubComplexHighConv: GINE edge conv + 2x (Linear -> BN(train) -> ReLU)
// N=100000, E=600000, NB=50000, C=H=128. fp32 in/out, bf16 internal.
//
// R6: GEMM column-stat atomics removed. Previous version fired 512 device
//     atomics/block into 8 cache lines (osum/osq) -> ~50k same-line RMWs
//     per line serialized the whole (fully co-resident) grid: gemm ran 67us
//     with MfmaUtil 1.7%. Now: per-wave stats -> LDS cross-wave reduce ->
//     ONE coalesced 256-float partial row per block (plain stores into dead
//     d_out scratch), folded by a tiny k_red kernel (25 atomics/address).
// Pipeline (8 dispatches):
//   k_front   : zero cnt/stats + W->bf16 WT transpose + x,x0 -> bf16
//   k_scatter : fixed-capacity(32) slot lists, slots[d*32+pos]={src,bri}
//   k_aggr    : aggr = bf16((1+eps)*xb + sum relu(xb[s]+x0b[b])), 2 halves
//   k_gemmb   : h1 = aggr@W1+b1 (bf16 in/out, in-place) + per-block partials
//   k_red     : partials -> sum1|sq1
//   k_gemmb   : h2 = relu(BN1(h1))@W2+b2 (BN1 folded) + per-block partials
//   k_red     : partials -> sum2|sq2
//   k_bnrelu  : out = relu(BN2(h2)) fp32
// ws: slots(25.6M) cnt stats WT1 WT2 abuf(25.6M) ~51.7MB.
// d_out scratch: xb|x0b (front/aggr phase); partials 800KB (gemm phase).
// ---------------------------------------------------------------------------

typedef __attribute__((ext_vector_type(8))) short bf16x8;
typedef __attribute__((ext_vector_type(4))) float floatx4;

__device__ __forceinline__ unsigned short f2bf(float f) {
  unsigned u = __float_as_uint(f);
  u += 0x7fff + ((u >> 16) & 1);   // RNE
  return (unsigned short)(u >> 16);
}
__device__ __forceinline__ unsigned pk2(float a, float b) {
  return (unsigned)f2bf(a) | ((unsigned)f2bf(b) << 16);
}
__device__ __forceinline__ float bflo(unsigned u) { return __uint_as_float(u << 16); }
__device__ __forceinline__ float bfhi(unsigned u) { return __uint_as_float(u & 0xffff0000u); }

// ---- front: zero cnt+stats, transpose W1/W2 to bf16, convert x/x0 ---------
__global__ __launch_bounds__(256) void k_front(
    const float* __restrict__ x, const float* __restrict__ x0,
    const float* __restrict__ W1, const float* __restrict__ W2,
    unsigned short* __restrict__ WT1, unsigned short* __restrict__ WT2,
    uint4* __restrict__ zbase, int zitems, int zblocks,
    uint4* __restrict__ xb, int nx,
    uint4* __restrict__ x0b, int nx0) {
  int b = blockIdx.x;
  int tid = threadIdx.x;
  if (b < 2) {                       // W transpose: [128k][128n] -> bf16 [n][k]
    const float* W = b ? W2 : W1;
    unsigned short* WT = b ? WT2 : WT1;
#pragma unroll
    for (int i = 0; i < 16; ++i) {
      int g = tid + i * 256;
      int k = g >> 5;
      int n0 = (g & 31) * 4;
      float4 v = *(const float4*)(W + k * 128 + n0);
      WT[(n0 + 0) * 128 + k] = f2bf(v.x);
      WT[(n0 + 1) * 128 + k] = f2bf(v.y);
      WT[(n0 + 2) * 128 + k] = f2bf(v.z);
      WT[(n0 + 3) * 128 + k] = f2bf(v.w);
    }
    return;
  }
  if (b < 2 + zblocks) {             // zero cnt + stats
    int t = (b - 2) * 256 + tid;
    if (t < zitems) zbase[t] = make_uint4(0, 0, 0, 0);
    return;
  }
  int t = (b - 2 - zblocks) * 256 + tid;   // fp32 -> bf16, 8 elems/thread
  const float* s;
  uint4* d;
  if (t < nx) { s = x + (size_t)t * 8; d = xb + t; }
  else {
    t -= nx;
    if (t >= nx0) return;
    s = x0 + (size_t)t * 8; d = x0b + t;
  }
  float4 a = *(const float4*)s;
  float4 c = *(const float4*)(s + 4);
  uint4 o;
  o.x = pk2(a.x, a.y); o.y = pk2(a.z, a.w);
  o.z = pk2(c.x, c.y); o.w = pk2(c.z, c.w);
  *d = o;
}

// ---- slot-list build: one 8B store per edge -------------------------------
__global__ __launch_bounds__(256) void k_scatter(
    const int* __restrict__ src, const int* __restrict__ dst,
    const int* __restrict__ bri, int* __restrict__ cnt,
    int2* __restrict__ slots, int E_) {
  int e = blockIdx.x * 256 + threadIdx.x;
  if (e >= E_) return;
  int d = dst[e];
  int pos = atomicAdd(&cnt[d], 1);
  if (pos < 32) slots[d * 32 + pos] = make_int2(src[e], bri[e]);
}

// ---- aggregation: 8 lanes/node x 2 channel-halves (grid.y), fp32 acc ------
// Half-pass live footprint 19.2MB (vs 38.4 full) -> better L2 hit.
__global__ __launch_bounds__(256) void k_aggr(
    const uint4* __restrict__ xb, const uint4* __restrict__ x0b,
    const int* __restrict__ cnt, const int2* __restrict__ slots,
    const float* __restrict__ eps, uint4* __restrict__ aggr, int n) {
  int tid = threadIdx.x;
  int node = blockIdx.x * 32 + (tid >> 3);
  if (node >= n) return;
  int q = (tid & 7) + blockIdx.y * 8;    // uint4 index within the 16-chunk row
  float s = 1.0f + eps[0];
  float acc[8];
  uint4 xi = xb[(size_t)node * 16 + q];
  acc[0] = s * bflo(xi.x); acc[1] = s * bfhi(xi.x);
  acc[2] = s * bflo(xi.y); acc[3] = s * bfhi(xi.y);
  acc[4] = s * bflo(xi.z); acc[5] = s * bfhi(xi.z);
  acc[6] = s * bflo(xi.w); acc[7] = s * bfhi(xi.w);
  int end = cnt[node];
  if (end > 32) end = 32;
  int base = node * 32;
  for (int j = 0; j < end; ++j) {
    int2 p = slots[base + j];        // broadcast within 8-lane group
    uint4 xa = xb[(size_t)p.x * 16 + q];
    uint4 ea = x0b[(size_t)p.y * 16 + q];
    acc[0] += fmaxf(bflo(xa.x) + bflo(ea.x), 0.f);
    acc[1] += fmaxf(bfhi(xa.x) + bfhi(ea.x), 0.f);
    acc[2] += fmaxf(bflo(xa.y) + bflo(ea.y), 0.f);
    acc[3] += fmaxf(bfhi(xa.y) + bfhi(ea.y), 0.f);
    acc[4] += fmaxf(bflo(xa.z) + bflo(ea.z), 0.f);
    acc[5] += fmaxf(bfhi(xa.z) + bfhi(ea.z), 0.f);
    acc[6] += fmaxf(bflo(xa.w) + bflo(ea.w), 0.f);
    acc[7] += fmaxf(bfhi(xa.w) + bfhi(ea.w), 0.f);
  }
  uint4 o;
  o.x = pk2(acc[0], acc[1]); o.y = pk2(acc[2], acc[3]);
  o.z = pk2(acc[4], acc[5]); o.w = pk2(acc[6], acc[7]);
  aggr[(size_t)node * 16 + q] = o;
}

// ---- bf16 MFMA GEMM, bf16 in/out, input-BN fold, output partial stats -----
// 128x128 tile/block, KC=64 two-chunk, staging pitch 72 shorts. Epilogue
// repacks C through LDS (pitch 136 = 16B-aligned rows) for coalesced stores.
// Column stats: per-wave shuffle reduce -> 2KB LDS cross-wave reduce ->
// one coalesced 256-float partial row per block (NO contended atomics).
// A/Out alias in place: all A reads (staging) precede epilogue stores.
__global__ __launch_bounds__(256) void k_gemmb(
    const unsigned short* A, const unsigned short* __restrict__ WT,
    const float* __restrict__ bias,
    const float* __restrict__ psum, const float* __restrict__ psq,
    const float* __restrict__ gam, const float* __restrict__ bet,
    unsigned short* Out,
    float* __restrict__ part,        // [gridDim.x][256]: sum(128)|sq(128)
    int nrows, float inv_n, int fuse) {
  __shared__ unsigned short LDSraw[128 * 144];   // staging: As|Bs; epilogue: C
  unsigned short* As = LDSraw;                   // pitch 72
  unsigned short* Bs = LDSraw + 128 * 72;        // pitch 72
  __shared__ float sL[128], hL[128];
  __shared__ float redS[4][64], redQ[4][64];     // cross-wave stat reduce
  int tid = threadIdx.x;
  if (fuse && tid < 128) {           // fold input BN from raw stats
    float mu = psum[tid] * inv_n;
    float var = psq[tid] * inv_n - mu * mu;
    float rs = rsqrtf(var + 1e-5f);
    float sc = gam[tid] * rs;
    sL[tid] = sc;
    hL[tid] = bet[tid] - mu * sc;
  }
  __syncthreads();

  int row0 = blockIdx.x * 128;
  int lane = tid & 63;
  int wid = tid >> 6;
  int wr = (wid >> 1) * 64;
  int wc = (wid & 1) * 64;
  int lr = lane & 15;
  int quad = lane >> 4;

  floatx4 acc[4][4];
#pragma unroll
  for (int mi = 0; mi < 4; ++mi)
#pragma unroll
    for (int ni = 0; ni < 4; ++ni) acc[mi][ni] = (floatx4)0.0f;

  for (int kc = 0; kc < 128; kc += 64) {
    if (kc) __syncthreads();
    // stage A: 128 rows x 64 k bf16
#pragma unroll
    for (int i = 0; i < 4; ++i) {
      int g = tid + i * 256;        // 1024 chunks
      int r = g >> 3;
      int c8 = g & 7;
      int row = row0 + r;
      uint4 v = make_uint4(0, 0, 0, 0);
      if (row < nrows)
        v = *(const uint4*)(A + (size_t)row * 128 + kc + c8 * 8);
      if (fuse) {
        int k = kc + c8 * 8;
        v.x = pk2(fmaxf(fmaf(sL[k + 0], bflo(v.x), hL[k + 0]), 0.f),
                  fmaxf(fmaf(sL[k + 1], bfhi(v.x), hL[k + 1]), 0.f));
        v.y = pk2(fmaxf(fmaf(sL[k + 2], bflo(v.y), hL[k + 2]), 0.f),
                  fmaxf(fmaf(sL[k + 3], bfhi(v.y), hL[k + 3]), 0.f));
        v.z = pk2(fmaxf(fmaf(sL[k + 4], bflo(v.z), hL[k + 4]), 0.f),
                  fmaxf(fmaf(sL[k + 5], bfhi(v.z), hL[k + 5]), 0.f));
        v.w = pk2(fmaxf(fmaf(sL[k + 6], bflo(v.w), hL[k + 6]), 0.f),
                  fmaxf(fmaf(sL[k + 7], bfhi(v.w), hL[k + 7]), 0.f));
      }
      *(uint4*)&As[r * 72 + c8 * 8] = v;
    }
    // stage B: 128 n x 64 k bf16
#pragma unroll
    for (int i = 0; i < 4; ++i) {
      int g = tid + i * 256;
      int nn = g >> 3;
      int c8 = g & 7;
      *(uint4*)&Bs[nn * 72 + c8 * 8] =
          *(const uint4*)(WT + (size_t)nn * 128 + kc + c8 * 8);
    }
    __syncthreads();
#pragma unroll
    for (int ks = 0; ks < 2; ++ks) {
      int k0 = ks * 32 + quad * 8;
      bf16x8 af[4], bfr[4];
#pragma unroll
      for (int mi = 0; mi < 4; ++mi)
        af[mi] = *(const bf16x8*)&As[(wr + mi * 16 + lr) * 72 + k0];
#pragma unroll
      for (int ni = 0; ni < 4; ++ni)
        bfr[ni] = *(const bf16x8*)&Bs[(wc + ni * 16 + lr) * 72 + k0];
#pragma unroll
      for (int mi = 0; mi < 4; ++mi)
#pragma unroll
        for (int ni = 0; ni < 4; ++ni)
          acc[mi][ni] = __builtin_amdgcn_mfma_f32_16x16x32_bf16(
              af[mi], bfr[ni], acc[mi][ni], 0, 0, 0);
    }
  }
  __syncthreads();   // LDS free for epilogue repack

  // epilogue: + bias, fp32 stats from regs, bf16 repack via LDS
  float bv[4];
#pragma unroll
  for (int ni = 0; ni < 4; ++ni) bv[ni] = bias[wc + ni * 16 + lr];
  float s_sum[4] = {0.f, 0.f, 0.f, 0.f};
  float s_sq[4]  = {0.f, 0.f, 0.f, 0.f};
#pragma unroll
  for (int mi = 0; mi < 4; ++mi) {
#pragma unroll
    for (int r = 0; r < 4; ++r) {
      int rl = wr + mi * 16 + quad * 4 + r;     // C/D: row=quad*4+reg
      bool ok = (row0 + rl) < nrows;
#pragma unroll
      for (int ni = 0; ni < 4; ++ni) {
        int col = wc + ni * 16 + lr;            // C/D: col=lane&15
        float v = acc[mi][ni][r] + bv[ni];
        LDSraw[rl * 136 + col] = f2bf(v);
        if (ok) { s_sum[ni] += v; s_sq[ni] += v * v; }
      }
    }
  }
#pragma unroll
  for (int ni = 0; ni < 4; ++ni) {
    s_sum[ni] += __shfl_xor(s_sum[ni], 16, 64);
    s_sum[ni] += __shfl_xor(s_sum[ni], 32, 64);
    s_sq[ni]  += __shfl_xor(s_sq[ni], 16, 64);
    s_sq[ni]  += __shfl_xor(s_sq[ni], 32, 64);
  }
  if (quad == 0) {                   // per-wave col partials -> LDS
#pragma unroll
    for (int ni = 0; ni < 4; ++ni) {
      redS[wid][ni * 16 + lr] = s_sum[ni];
      redQ[wid][ni * 16 + lr] = s_sq[ni];
    }
  }
  __syncthreads();
  // block-level partial row: cols 0-63 from waves {0,2}, 64-127 from {1,3}
  if (tid < 128) {
    int half = tid >> 6;
    int cl = tid & 63;
    part[(size_t)blockIdx.x * 256 + tid] = redS[half][cl] + redS[half + 2][cl];
    part[(size_t)blockIdx.x * 256 + 128 + tid] = redQ[half][cl] + redQ[half + 2][cl];
  }
  // coalesced store: 2048 uint4 chunks (128 rows x 16 chunks)
#pragma unroll
  for (int i = 0; i < 8; ++i) {
    int g = tid + i * 256;
    int r = g >> 4;
    int c8 = g & 15;
    if (row0 + r < nrows)
      *(uint4*)(Out + (size_t)(row0 + r) * 128 + c8 * 8) =
          *(const uint4*)&LDSraw[r * 136 + c8 * 8];
  }
}

// ---- fold per-block partial stat rows into sum|sq (256 floats at dst) -----
// 32 rows/block, coalesced 1KB row reads; ~25 atomics/address: negligible.
__global__ __launch_bounds__(256) void k_red(
    const float* __restrict__ part, float* __restrict__ dst, int nb) {
  int c = threadIdx.x;              // 0..255 -> sum(0-127)|sq(128-255)
  int r0 = blockIdx.x * 32;
  int r1 = r0 + 32;
  if (r1 > nb) r1 = nb;
  float a = 0.f;
  for (int r = r0; r < r1; ++r) a += part[(size_t)r * 256 + c];
  unsafeAtomicAdd(&dst[c], a);
}

// ---- final BN2+ReLU (folds stats in prologue), bf16 -> fp32 out -----------
__global__ __launch_bounds__(256) void k_bnrelu(
    const uint4* __restrict__ h, const float* __restrict__ psum,
    const float* __restrict__ psq, const float* __restrict__ gam,
    const float* __restrict__ bet, float* __restrict__ out,
    int items, float inv_n) {
  __shared__ float sL[128], hL[128];
  int tid = threadIdx.x;
  if (tid < 128) {
    float mu = psum[tid] * inv_n;
    float var = psq[tid] * inv_n - mu * mu;
    float rs = rsqrtf(var + 1e-5f);
    float sc = gam[tid] * rs;
    sL[tid] = sc;
    hL[tid] = bet[tid] - mu * sc;
  }
  __syncthreads();
  int t = blockIdx.x * 256 + tid;
  if (t >= items) return;
  int c = (t & 15) * 8;
  uint4 v = h[t];
  float4 o1, o2;
  o1.x = fmaxf(fmaf(sL[c + 0], bflo(v.x), hL[c + 0]), 0.f);
  o1.y = fmaxf(fmaf(sL[c + 1], bfhi(v.x), hL[c + 1]), 0.f);
  o1.z = fmaxf(fmaf(sL[c + 2], bflo(v.y), hL[c + 2]), 0.f);
  o1.w = fmaxf(fmaf(sL[c + 3], bfhi(v.y), hL[c + 3]), 0.f);
  o2.x = fmaxf(fmaf(sL[c + 4], bflo(v.z), hL[c + 4]), 0.f);
  o2.y = fmaxf(fmaf(sL[c + 5], bfhi(v.z), hL[c + 5]), 0.f);
  o2.z = fmaxf(fmaf(sL[c + 6], bflo(v.w), hL[c + 6]), 0.f);
  o2.w = fmaxf(fmaf(sL[c + 7], bfhi(v.w), hL[c + 7]), 0.f);
  ((float4*)out)[(size_t)t * 2 + 0] = o1;
  ((float4*)out)[(size_t)t * 2 + 1] = o2;
}

extern "C" void kernel_launch(void* const* d_in, const int* in_sizes, int n_in,
                              void* d_out, int out_size, void* d_ws, size_t ws_size,
                              hipStream_t stream) {
  const float* x   = (const float*)d_in[0];
  const float* x0  = (const float*)d_in[1];
  const int*   ei  = (const int*)d_in[2];    // [2][E]: row0=src, row1=dst
  const int*   bi  = (const int*)d_in[3];
  const float* W1  = (const float*)d_in[4];
  const float* b1  = (const float*)d_in[5];
  const float* g1  = (const float*)d_in[6];
  const float* be1 = (const float*)d_in[7];
  const float* W2  = (const float*)d_in[8];
  const float* b2  = (const float*)d_in[9];
  const float* g2  = (const float*)d_in[10];
  const float* be2 = (const float*)d_in[11];
  const float* eps = (const float*)d_in[12];

  int N  = in_sizes[0] / 128;
  int NB = in_sizes[1] / 128;
  int E_ = in_sizes[3];
  const int* srcp = ei;
  const int* dstp = ei + E_;

  // ws layout (~51.7 MB): slots | cnt | stats | WT1 | WT2 | abuf
  int2* slots = (int2*)d_ws;                                // N*32 int2
  int* cnt    = (int*)(slots + (size_t)N * 32);             // N ints
  float* stats = (float*)(cnt + N);                         // 512 floats
  float* sum1 = stats;                                      // sum1|sq1 contiguous
  float* sum2 = stats + 256;                                // sum2|sq2 contiguous
  unsigned short* WT1  = (unsigned short*)(stats + 512);    // 16384
  unsigned short* WT2  = WT1 + 16384;                       // 16384
  unsigned short* abuf = WT2 + 16384;                       // N*128 bf16

  // d_out scratch: xb | x0b during front/aggr; partials during gemm phase
  unsigned short* xb  = (unsigned short*)d_out;             // N*128
  unsigned short* x0b = xb + (size_t)N * 128;               // NB*128
  float* part = (float*)d_out;       // gblocks x 256 (xb dead after k_aggr)

  int zitems  = (N + 512 + 3) / 4;           // uint4 slots covering cnt+stats
  int zblocks = (zitems + 255) / 256;
  int nx  = N * 16;                          // uint4 cvt items for x
  int nx0 = NB * 16;
  int cvtblocks = (nx + nx0 + 255) / 256;
  float inv_n = 1.0f / (float)N;

  k_front<<<2 + zblocks + cvtblocks, 256, 0, stream>>>(
      x, x0, W1, W2, WT1, WT2, (uint4*)cnt, zitems, zblocks,
      (uint4*)xb, nx, (uint4*)x0b, nx0);

  k_scatter<<<(E_ + 255) / 256, 256, 0, stream>>>(srcp, dstp, bi, cnt,
                                                  slots, E_);

  dim3 agrid((N * 8 + 255) / 256, 2);
  k_aggr<<<agrid, 256, 0, stream>>>(
      (const uint4*)xb, (const uint4*)x0b, cnt, slots, eps,
      (uint4*)abuf, N);

  int gblocks = (N + 127) / 128;
  int rblocks = (gblocks + 31) / 32;
  k_gemmb<<<gblocks, 256, 0, stream>>>(abuf, WT1, b1, nullptr, nullptr,
                                       nullptr, nullptr, abuf, part,
                                       N, inv_n, 0);
  k_red<<<rblocks, 256, 0, stream>>>(part, sum1, gblocks);
  k_gemmb<<<gblocks, 256, 0, stream>>>(abuf, WT2, b2, sum1, sum1 + 128,
                                       g1, be1, abuf, part, N, inv_n, 1);
  k_red<<<rblocks, 256, 0, stream>>>(part, sum2, gblocks);

  k_bnrelu<<<(N * 16 + 255) / 256, 256, 0, stream>>>(
      (const uint4*)abuf, sum2, sum2 + 128, g2, be2, (float*)d_out,
      N * 16, inv_n);
}

// Round 2
// 294.775 us; speedup vs baseline: 1.1758x; 1.0162x over previous
//
#include <hip/hip_runtime.h>

// ---------------------------------------------------------------------------
// SubComplexHighConv: GINE edge conv + 2x (Linear -> BN(train) -> ReLU)
// N=100000, E=600000, NB=50000, C=H=128. fp32 in/out, bf16 internal.
//
// R7: k_aggr was latency-bound (VGPR=20: rolled loop, 1 gather chain in
//     flight; 33% VALU, 51% BW). Inner edge loop now 4-wide unrolled with
//     int4 paired slot loads -> 8 independent 16B gathers in flight per
//     group. Traffic unchanged; pure MLP increase.
// Pipeline (8 dispatches):
//   k_front   : zero cnt/stats + W->bf16 WT transpose + x,x0 -> bf16
//   k_scatter : fixed-capacity(32) slot lists, slots[d*32+pos]={src,bri}
//   k_aggr    : aggr = bf16((1+eps)*xb + sum relu(xb[s]+x0b[b])), 2 halves
//   k_gemmb   : h1 = aggr@W1+b1 (bf16 in/out, in-place) + per-block partials
//   k_red     : partials -> sum1|sq1
//   k_gemmb   : h2 = relu(BN1(h1))@W2+b2 (BN1 folded) + per-block partials
//   k_red     : partials -> sum2|sq2
//   k_bnrelu  : out = relu(BN2(h2)) fp32
// ws: slots(25.6M) cnt stats WT1 WT2 abuf(25.6M) ~51.7MB.
// d_out scratch: xb|x0b (front/aggr phase); partials 800KB (gemm phase).
// ---------------------------------------------------------------------------

typedef __attribute__((ext_vector_type(8))) short bf16x8;
typedef __attribute__((ext_vector_type(4))) float floatx4;

__device__ __forceinline__ unsigned short f2bf(float f) {
  unsigned u = __float_as_uint(f);
  u += 0x7fff + ((u >> 16) & 1);   // RNE
  return (unsigned short)(u >> 16);
}
__device__ __forceinline__ unsigned pk2(float a, float b) {
  return (unsigned)f2bf(a) | ((unsigned)f2bf(b) << 16);
}
__device__ __forceinline__ float bflo(unsigned u) { return __uint_as_float(u << 16); }
__device__ __forceinline__ float bfhi(unsigned u) { return __uint_as_float(u & 0xffff0000u); }

// ---- front: zero cnt+stats, transpose W1/W2 to bf16, convert x/x0 ---------
__global__ __launch_bounds__(256) void k_front(
    const float* __restrict__ x, const float* __restrict__ x0,
    const float* __restrict__ W1, const float* __restrict__ W2,
    unsigned short* __restrict__ WT1, unsigned short* __restrict__ WT2,
    uint4* __restrict__ zbase, int zitems, int zblocks,
    uint4* __restrict__ xb, int nx,
    uint4* __restrict__ x0b, int nx0) {
  int b = blockIdx.x;
  int tid = threadIdx.x;
  if (b < 2) {                       // W transpose: [128k][128n] -> bf16 [n][k]
    const float* W = b ? W2 : W1;
    unsigned short* WT = b ? WT2 : WT1;
#pragma unroll
    for (int i = 0; i < 16; ++i) {
      int g = tid + i * 256;
      int k = g >> 5;
      int n0 = (g & 31) * 4;
      float4 v = *(const float4*)(W + k * 128 + n0);
      WT[(n0 + 0) * 128 + k] = f2bf(v.x);
      WT[(n0 + 1) * 128 + k] = f2bf(v.y);
      WT[(n0 + 2) * 128 + k] = f2bf(v.z);
      WT[(n0 + 3) * 128 + k] = f2bf(v.w);
    }
    return;
  }
  if (b < 2 + zblocks) {             // zero cnt + stats
    int t = (b - 2) * 256 + tid;
    if (t < zitems) zbase[t] = make_uint4(0, 0, 0, 0);
    return;
  }
  int t = (b - 2 - zblocks) * 256 + tid;   // fp32 -> bf16, 8 elems/thread
  const float* s;
  uint4* d;
  if (t < nx) { s = x + (size_t)t * 8; d = xb + t; }
  else {
    t -= nx;
    if (t >= nx0) return;
    s = x0 + (size_t)t * 8; d = x0b + t;
  }
  float4 a = *(const float4*)s;
  float4 c = *(const float4*)(s + 4);
  uint4 o;
  o.x = pk2(a.x, a.y); o.y = pk2(a.z, a.w);
  o.z = pk2(c.x, c.y); o.w = pk2(c.z, c.w);
  *d = o;
}

// ---- slot-list build: one 8B store per edge -------------------------------
__global__ __launch_bounds__(256) void k_scatter(
    const int* __restrict__ src, const int* __restrict__ dst,
    const int* __restrict__ bri, int* __restrict__ cnt,
    int2* __restrict__ slots, int E_) {
  int e = blockIdx.x * 256 + threadIdx.x;
  if (e >= E_) return;
  int d = dst[e];
  int pos = atomicAdd(&cnt[d], 1);
  if (pos < 32) slots[d * 32 + pos] = make_int2(src[e], bri[e]);
}

// ---- aggregation: 8 lanes/node x 2 channel-halves (grid.y), fp32 acc ------
// Half-pass live footprint 19.2MB; 4-wide edge unroll for gather MLP.
__device__ __forceinline__ void acc8(float* acc, uint4 xa, uint4 ea) {
  acc[0] += fmaxf(bflo(xa.x) + bflo(ea.x), 0.f);
  acc[1] += fmaxf(bfhi(xa.x) + bfhi(ea.x), 0.f);
  acc[2] += fmaxf(bflo(xa.y) + bflo(ea.y), 0.f);
  acc[3] += fmaxf(bfhi(xa.y) + bfhi(ea.y), 0.f);
  acc[4] += fmaxf(bflo(xa.z) + bflo(ea.z), 0.f);
  acc[5] += fmaxf(bfhi(xa.z) + bfhi(ea.z), 0.f);
  acc[6] += fmaxf(bflo(xa.w) + bflo(ea.w), 0.f);
  acc[7] += fmaxf(bfhi(xa.w) + bfhi(ea.w), 0.f);
}

__global__ __launch_bounds__(256) void k_aggr(
    const uint4* __restrict__ xb, const uint4* __restrict__ x0b,
    const int* __restrict__ cnt, const int2* __restrict__ slots,
    const float* __restrict__ eps, uint4* __restrict__ aggr, int n) {
  int tid = threadIdx.x;
  int node = blockIdx.x * 32 + (tid >> 3);
  if (node >= n) return;
  int q = (tid & 7) + blockIdx.y * 8;    // uint4 index within the 16-chunk row
  float s = 1.0f + eps[0];
  float acc[8];
  uint4 xi = xb[(size_t)node * 16 + q];
  acc[0] = s * bflo(xi.x); acc[1] = s * bfhi(xi.x);
  acc[2] = s * bflo(xi.y); acc[3] = s * bfhi(xi.y);
  acc[4] = s * bflo(xi.z); acc[5] = s * bfhi(xi.z);
  acc[6] = s * bflo(xi.w); acc[7] = s * bfhi(xi.w);
  int end = cnt[node];
  if (end > 32) end = 32;
  int base = node * 32;
  int j = 0;
  // 4-wide: two int4 slot loads (16B each, aligned), 8 gathers in flight
  for (; j + 4 <= end; j += 4) {
    int4 pa = *(const int4*)(slots + base + j);        // slots j, j+1
    int4 pb = *(const int4*)(slots + base + j + 2);    // slots j+2, j+3
    uint4 xa0 = xb[(size_t)pa.x * 16 + q];
    uint4 ea0 = x0b[(size_t)pa.y * 16 + q];
    uint4 xa1 = xb[(size_t)pa.z * 16 + q];
    uint4 ea1 = x0b[(size_t)pa.w * 16 + q];
    uint4 xa2 = xb[(size_t)pb.x * 16 + q];
    uint4 ea2 = x0b[(size_t)pb.y * 16 + q];
    uint4 xa3 = xb[(size_t)pb.z * 16 + q];
    uint4 ea3 = x0b[(size_t)pb.w * 16 + q];
    acc8(acc, xa0, ea0);
    acc8(acc, xa1, ea1);
    acc8(acc, xa2, ea2);
    acc8(acc, xa3, ea3);
  }
  if (j + 2 <= end) {                 // 2-wide tail
    int4 pa = *(const int4*)(slots + base + j);
    uint4 xa0 = xb[(size_t)pa.x * 16 + q];
    uint4 ea0 = x0b[(size_t)pa.y * 16 + q];
    uint4 xa1 = xb[(size_t)pa.z * 16 + q];
    uint4 ea1 = x0b[(size_t)pa.w * 16 + q];
    acc8(acc, xa0, ea0);
    acc8(acc, xa1, ea1);
    j += 2;
  }
  if (j < end) {                      // 1-wide tail
    int2 p = slots[base + j];
    uint4 xa0 = xb[(size_t)p.x * 16 + q];
    uint4 ea0 = x0b[(size_t)p.y * 16 + q];
    acc8(acc, xa0, ea0);
  }
  uint4 o;
  o.x = pk2(acc[0], acc[1]); o.y = pk2(acc[2], acc[3]);
  o.z = pk2(acc[4], acc[5]); o.w = pk2(acc[6], acc[7]);
  aggr[(size_t)node * 16 + q] = o;
}

// ---- bf16 MFMA GEMM, bf16 in/out, input-BN fold, output partial stats -----
// 128x128 tile/block, KC=64 two-chunk, staging pitch 72 shorts. Epilogue
// repacks C through LDS (pitch 136 = 16B-aligned rows) for coalesced stores.
// Column stats: per-wave shuffle reduce -> 2KB LDS cross-wave reduce ->
// one coalesced 256-float partial row per block (NO contended atomics).
// A/Out alias in place: all A reads (staging) precede epilogue stores.
__global__ __launch_bounds__(256) void k_gemmb(
    const unsigned short* A, const unsigned short* __restrict__ WT,
    const float* __restrict__ bias,
    const float* __restrict__ psum, const float* __restrict__ psq,
    const float* __restrict__ gam, const float* __restrict__ bet,
    unsigned short* Out,
    float* __restrict__ part,        // [gridDim.x][256]: sum(128)|sq(128)
    int nrows, float inv_n, int fuse) {
  __shared__ unsigned short LDSraw[128 * 144];   // staging: As|Bs; epilogue: C
  unsigned short* As = LDSraw;                   // pitch 72
  unsigned short* Bs = LDSraw + 128 * 72;        // pitch 72
  __shared__ float sL[128], hL[128];
  __shared__ float redS[4][64], redQ[4][64];     // cross-wave stat reduce
  int tid = threadIdx.x;
  if (fuse && tid < 128) {           // fold input BN from raw stats
    float mu = psum[tid] * inv_n;
    float var = psq[tid] * inv_n - mu * mu;
    float rs = rsqrtf(var + 1e-5f);
    float sc = gam[tid] * rs;
    sL[tid] = sc;
    hL[tid] = bet[tid] - mu * sc;
  }
  __syncthreads();

  int row0 = blockIdx.x * 128;
  int lane = tid & 63;
  int wid = tid >> 6;
  int wr = (wid >> 1) * 64;
  int wc = (wid & 1) * 64;
  int lr = lane & 15;
  int quad = lane >> 4;

  floatx4 acc[4][4];
#pragma unroll
  for (int mi = 0; mi < 4; ++mi)
#pragma unroll
    for (int ni = 0; ni < 4; ++ni) acc[mi][ni] = (floatx4)0.0f;

  for (int kc = 0; kc < 128; kc += 64) {
    if (kc) __syncthreads();
    // stage A: 128 rows x 64 k bf16
#pragma unroll
    for (int i = 0; i < 4; ++i) {
      int g = tid + i * 256;        // 1024 chunks
      int r = g >> 3;
      int c8 = g & 7;
      int row = row0 + r;
      uint4 v = make_uint4(0, 0, 0, 0);
      if (row < nrows)
        v = *(const uint4*)(A + (size_t)row * 128 + kc + c8 * 8);
      if (fuse) {
        int k = kc + c8 * 8;
        v.x = pk2(fmaxf(fmaf(sL[k + 0], bflo(v.x), hL[k + 0]), 0.f),
                  fmaxf(fmaf(sL[k + 1], bfhi(v.x), hL[k + 1]), 0.f));
        v.y = pk2(fmaxf(fmaf(sL[k + 2], bflo(v.y), hL[k + 2]), 0.f),
                  fmaxf(fmaf(sL[k + 3], bfhi(v.y), hL[k + 3]), 0.f));
        v.z = pk2(fmaxf(fmaf(sL[k + 4], bflo(v.z), hL[k + 4]), 0.f),
                  fmaxf(fmaf(sL[k + 5], bfhi(v.z), hL[k + 5]), 0.f));
        v.w = pk2(fmaxf(fmaf(sL[k + 6], bflo(v.w), hL[k + 6]), 0.f),
                  fmaxf(fmaf(sL[k + 7], bfhi(v.w), hL[k + 7]), 0.f));
      }
      *(uint4*)&As[r * 72 + c8 * 8] = v;
    }
    // stage B: 128 n x 64 k bf16
#pragma unroll
    for (int i = 0; i < 4; ++i) {
      int g = tid + i * 256;
      int nn = g >> 3;
      int c8 = g & 7;
      *(uint4*)&Bs[nn * 72 + c8 * 8] =
          *(const uint4*)(WT + (size_t)nn * 128 + kc + c8 * 8);
    }
    __syncthreads();
#pragma unroll
    for (int ks = 0; ks < 2; ++ks) {
      int k0 = ks * 32 + quad * 8;
      bf16x8 af[4], bfr[4];
#pragma unroll
      for (int mi = 0; mi < 4; ++mi)
        af[mi] = *(const bf16x8*)&As[(wr + mi * 16 + lr) * 72 + k0];
#pragma unroll
      for (int ni = 0; ni < 4; ++ni)
        bfr[ni] = *(const bf16x8*)&Bs[(wc + ni * 16 + lr) * 72 + k0];
#pragma unroll
      for (int mi = 0; mi < 4; ++mi)
#pragma unroll
        for (int ni = 0; ni < 4; ++ni)
          acc[mi][ni] = __builtin_amdgcn_mfma_f32_16x16x32_bf16(
              af[mi], bfr[ni], acc[mi][ni], 0, 0, 0);
    }
  }
  __syncthreads();   // LDS free for epilogue repack

  // epilogue: + bias, fp32 stats from regs, bf16 repack via LDS
  float bv[4];
#pragma unroll
  for (int ni = 0; ni < 4; ++ni) bv[ni] = bias[wc + ni * 16 + lr];
  float s_sum[4] = {0.f, 0.f, 0.f, 0.f};
  float s_sq[4]  = {0.f, 0.f, 0.f, 0.f};
#pragma unroll
  for (int mi = 0; mi < 4; ++mi) {
#pragma unroll
    for (int r = 0; r < 4; ++r) {
      int rl = wr + mi * 16 + quad * 4 + r;     // C/D: row=quad*4+reg
      bool ok = (row0 + rl) < nrows;
#pragma unroll
      for (int ni = 0; ni < 4; ++ni) {
        int col = wc + ni * 16 + lr;            // C/D: col=lane&15
        float v = acc[mi][ni][r] + bv[ni];
        LDSraw[rl * 136 + col] = f2bf(v);
        if (ok) { s_sum[ni] += v; s_sq[ni] += v * v; }
      }
    }
  }
#pragma unroll
  for (int ni = 0; ni < 4; ++ni) {
    s_sum[ni] += __shfl_xor(s_sum[ni], 16, 64);
    s_sum[ni] += __shfl_xor(s_sum[ni], 32, 64);
    s_sq[ni]  += __shfl_xor(s_sq[ni], 16, 64);
    s_sq[ni]  += __shfl_xor(s_sq[ni], 32, 64);
  }
  if (quad == 0) {                   // per-wave col partials -> LDS
#pragma unroll
    for (int ni = 0; ni < 4; ++ni) {
      redS[wid][ni * 16 + lr] = s_sum[ni];
      redQ[wid][ni * 16 + lr] = s_sq[ni];
    }
  }
  __syncthreads();
  // block-level partial row: cols 0-63 from waves {0,2}, 64-127 from {1,3}
  if (tid < 128) {
    int half = tid >> 6;
    int cl = tid & 63;
    part[(size_t)blockIdx.x * 256 + tid] = redS[half][cl] + redS[half + 2][cl];
    part[(size_t)blockIdx.x * 256 + 128 + tid] = redQ[half][cl] + redQ[half + 2][cl];
  }
  // coalesced store: 2048 uint4 chunks (128 rows x 16 chunks)
#pragma unroll
  for (int i = 0; i < 8; ++i) {
    int g = tid + i * 256;
    int r = g >> 4;
    int c8 = g & 15;
    if (row0 + r < nrows)
      *(uint4*)(Out + (size_t)(row0 + r) * 128 + c8 * 8) =
          *(const uint4*)&LDSraw[r * 136 + c8 * 8];
  }
}

// ---- fold per-block partial stat rows into sum|sq (256 floats at dst) -----
// 32 rows/block, coalesced 1KB row reads; ~25 atomics/address: negligible.
__global__ __launch_bounds__(256) void k_red(
    const float* __restrict__ part, float* __restrict__ dst, int nb) {
  int c = threadIdx.x;              // 0..255 -> sum(0-127)|sq(128-255)
  int r0 = blockIdx.x * 32;
  int r1 = r0 + 32;
  if (r1 > nb) r1 = nb;
  float a = 0.f;
  for (int r = r0; r < r1; ++r) a += part[(size_t)r * 256 + c];
  unsafeAtomicAdd(&dst[c], a);
}

// ---- final BN2+ReLU (folds stats in prologue), bf16 -> fp32 out -----------
__global__ __launch_bounds__(256) void k_bnrelu(
    const uint4* __restrict__ h, const float* __restrict__ psum,
    const float* __restrict__ psq, const float* __restrict__ gam,
    const float* __restrict__ bet, float* __restrict__ out,
    int items, float inv_n) {
  __shared__ float sL[128], hL[128];
  int tid = threadIdx.x;
  if (tid < 128) {
    float mu = psum[tid] * inv_n;
    float var = psq[tid] * inv_n - mu * mu;
    float rs = rsqrtf(var + 1e-5f);
    float sc = gam[tid] * rs;
    sL[tid] = sc;
    hL[tid] = bet[tid] - mu * sc;
  }
  __syncthreads();
  int t = blockIdx.x * 256 + tid;
  if (t >= items) return;
  int c = (t & 15) * 8;
  uint4 v = h[t];
  float4 o1, o2;
  o1.x = fmaxf(fmaf(sL[c + 0], bflo(v.x), hL[c + 0]), 0.f);
  o1.y = fmaxf(fmaf(sL[c + 1], bfhi(v.x), hL[c + 1]), 0.f);
  o1.z = fmaxf(fmaf(sL[c + 2], bflo(v.y), hL[c + 2]), 0.f);
  o1.w = fmaxf(fmaf(sL[c + 3], bfhi(v.y), hL[c + 3]), 0.f);
  o2.x = fmaxf(fmaf(sL[c + 4], bflo(v.z), hL[c + 4]), 0.f);
  o2.y = fmaxf(fmaf(sL[c + 5], bfhi(v.z), hL[c + 5]), 0.f);
  o2.z = fmaxf(fmaf(sL[c + 6], bflo(v.w), hL[c + 6]), 0.f);
  o2.w = fmaxf(fmaf(sL[c + 7], bfhi(v.w), hL[c + 7]), 0.f);
  ((float4*)out)[(size_t)t * 2 + 0] = o1;
  ((float4*)out)[(size_t)t * 2 + 1] = o2;
}

extern "C" void kernel_launch(void* const* d_in, const int* in_sizes, int n_in,
                              void* d_out, int out_size, void* d_ws, size_t ws_size,
                              hipStream_t stream) {
  const float* x   = (const float*)d_in[0];
  const float* x0  = (const float*)d_in[1];
  const int*   ei  = (const int*)d_in[2];    // [2][E]: row0=src, row1=dst
  const int*   bi  = (const int*)d_in[3];
  const float* W1  = (const float*)d_in[4];
  const float* b1  = (const float*)d_in[5];
  const float* g1  = (const float*)d_in[6];
  const float* be1 = (const float*)d_in[7];
  const float* W2  = (const float*)d_in[8];
  const float* b2  = (const float*)d_in[9];
  const float* g2  = (const float*)d_in[10];
  const float* be2 = (const float*)d_in[11];
  const float* eps = (const float*)d_in[12];

  int N  = in_sizes[0] / 128;
  int NB = in_sizes[1] / 128;
  int E_ = in_sizes[3];
  const int* srcp = ei;
  const int* dstp = ei + E_;

  // ws layout (~51.7 MB): slots | cnt | stats | WT1 | WT2 | abuf
  int2* slots = (int2*)d_ws;                                // N*32 int2
  int* cnt    = (int*)(slots + (size_t)N * 32);             // N ints
  float* stats = (float*)(cnt + N);                         // 512 floats
  float* sum1 = stats;                                      // sum1|sq1 contiguous
  float* sum2 = stats + 256;                                // sum2|sq2 contiguous
  unsigned short* WT1  = (unsigned short*)(stats + 512);    // 16384
  unsigned short* WT2  = WT1 + 16384;                       // 16384
  unsigned short* abuf = WT2 + 16384;                       // N*128 bf16

  // d_out scratch: xb | x0b during front/aggr; partials during gemm phase
  unsigned short* xb  = (unsigned short*)d_out;             // N*128
  unsigned short* x0b = xb + (size_t)N * 128;               // NB*128
  float* part = (float*)d_out;       // gblocks x 256 (xb dead after k_aggr)

  int zitems  = (N + 512 + 3) / 4;           // uint4 slots covering cnt+stats
  int zblocks = (zitems + 255) / 256;
  int nx  = N * 16;                          // uint4 cvt items for x
  int nx0 = NB * 16;
  int cvtblocks = (nx + nx0 + 255) / 256;
  float inv_n = 1.0f / (float)N;

  k_front<<<2 + zblocks + cvtblocks, 256, 0, stream>>>(
      x, x0, W1, W2, WT1, WT2, (uint4*)cnt, zitems, zblocks,
      (uint4*)xb, nx, (uint4*)x0b, nx0);

  k_scatter<<<(E_ + 255) / 256, 256, 0, stream>>>(srcp, dstp, bi, cnt,
                                                  slots, E_);

  dim3 agrid((N * 8 + 255) / 256, 2);
  k_aggr<<<agrid, 256, 0, stream>>>(
      (const uint4*)xb, (const uint4*)x0b, cnt, slots, eps,
      (uint4*)abuf, N);

  int gblocks = (N + 127) / 128;
  int rblocks = (gblocks + 31) / 32;
  k_gemmb<<<gblocks, 256, 0, stream>>>(abuf, WT1, b1, nullptr, nullptr,
                                       nullptr, nullptr, abuf, part,
                                       N, inv_n, 0);
  k_red<<<rblocks, 256, 0, stream>>>(part, sum1, gblocks);
  k_gemmb<<<gblocks, 256, 0, stream>>>(abuf, WT2, b2, sum1, sum1 + 128,
                                       g1, be1, abuf, part, N, inv_n, 1);
  k_red<<<rblocks, 256, 0, stream>>>(part, sum2, gblocks);

  k_bnrelu<<<(N * 16 + 255) / 256, 256, 0, stream>>>(
      (const uint4*)abuf, sum2, sum2 + 128, g2, be2, (float*)d_out,
      N * 16, inv_n);
}